// Round 2
// baseline (181.174 us; speedup 1.0000x reference)
//
#include <hip/hip_runtime.h>

#define B_    4
#define N_    20000
#define M_    20000
#define K_    16
#define CIN   64
#define CMID  16
#define COUT  67          // CIN + 3 additional channels
#define PPB   4           // one point per wave, 4 waves per block

typedef float float4_ __attribute__((ext_vector_type(4)));

__global__ __launch_bounds__(256, 4) void pconv_kernel(
    const float* __restrict__ in_feats,   // [B, N, 64]
    const int*   __restrict__ inds,       // [B, M, 16]
    const float* __restrict__ wn,         // [B, M, 16, 16]
    const float* __restrict__ addl,       // [B, M, 16, 3]
    float*       __restrict__ out)        // [B, M, 1072]
{
    const int tid   = threadIdx.x;
    const int lane  = tid & 63;
    const int wav   = tid >> 6;            // wave in block, 0..3
    const int c_low = lane >> 2;           // 0..15  (c within 16-channel group)
    const int j     = lane & 3;            // 0..3   (w-quad)

    // one point per wave; force scalar (SGPR) addressing for all per-point bases
    int bp = blockIdx.x * PPB + wav;
    bp = __builtin_amdgcn_readfirstlane(bp);
    const int b = bp / M_;

    const int*   pinds = inds + (long)bp * K_;
    const float* pwn   = wn   + (long)bp * (K_ * CMID);
    const float* padd  = addl + (long)bp * (K_ * 3);
    const float* bfeat = in_feats + (long)b * N_ * CIN;

    float4_ acc[4];                        // c = cc*16 + c_low, w = 4j..4j+3
    acc[0] = acc[1] = acc[2] = acc[3] = (float4_)0.f;
    float4_ acc2 = (float4_)0.f;           // tail channels c = 64 + (lane>>2), lanes 0..11
    const bool tail = lane < 12;
    const int  tc   = lane >> 2;           // 0..2 on tail lanes

    #pragma unroll 4
    for (int k = 0; k < K_; ++k) {
        const int idx = pinds[k];                          // s_load, uniform
        const float* row = bfeat + (long)idx * CIN;
        float4_ wv = *(const float4_*)(pwn + k * CMID + j * 4);   // wn[k][4j..4j+3]
        float f0 = row[      c_low];                       // 1 granule / point / instr
        float f1 = row[16  + c_low];
        float f2 = row[32  + c_low];
        float f3 = row[48  + c_low];
        float av = tail ? padd[k * 3 + tc] : 0.f;
        acc[0] += f0 * wv;
        acc[1] += f1 * wv;
        acc[2] += f2 * wv;
        acc[3] += f3 * wv;
        acc2   += av * wv;
    }

    // stores: 4 x 1KiB contiguous chunks per point + one 192B tail chunk
    float* pout = out + (long)bp * (COUT * CMID);
    #pragma unroll
    for (int cc = 0; cc < 4; ++cc) {
        *(float4_*)(pout + cc * 256 + lane * 4) = acc[cc];
    }
    if (tail) {
        *(float4_*)(pout + 1024 + lane * 4) = acc2;        // c=64..66, all w
    }
}

extern "C" void kernel_launch(void* const* d_in, const int* in_sizes, int n_in,
                              void* d_out, int out_size, void* d_ws, size_t ws_size,
                              hipStream_t stream) {
    const float* in_feats = (const float*)d_in[0];
    const int*   ninds    = (const int*)d_in[1];
    const float* wn       = (const float*)d_in[2];
    const float* addl     = (const float*)d_in[3];
    float*       out      = (float*)d_out;

    const int total_points = B_ * M_;            // 80000
    dim3 grid(total_points / PPB);               // 20000 blocks, 1 point/wave
    dim3 block(256);
    pconv_kernel<<<grid, block, 0, stream>>>(in_feats, ninds, wn, addl, out);
}